// Round 14
// baseline (44.289 us; speedup 1.0000x reference)
//
#include <hip/hip_runtime.h>
#include <math.h>

#define H 8
#define C 32
#define HC 256
#define KSL 32    // slices per graph
#define PB 16     // partial expsum blocks per head

__device__ __forceinline__ float wred_sum(float v) {
#pragma unroll
    for (int o = 32; o; o >>= 1) v += __shfl_xor(v, o, 64);
    return v;
}
__device__ __forceinline__ float4 red4_no(float4 v) {
#pragma unroll
    for (int o = 8; o < 64; o <<= 1) {
        v.x += __shfl_xor(v.x, o, 64);
        v.y += __shfl_xor(v.y, o, 64);
        v.z += __shfl_xor(v.z, o, 64);
        v.w += __shfl_xor(v.w, o, 64);
    }
    return v;
}
__device__ __forceinline__ int lower_bound(const int* __restrict__ a, int n, int key) {
    int lo = 0, hi = n;
    while (lo < hi) {                 // wave-uniform: all lanes same path
        const int mid = (lo + hi) >> 1;
        if (a[mid] < key) lo = mid + 1; else hi = mid;
    }
    return lo;
}

#define FMA8(XV, W0, W1)                                              \
    a0.x = fmaf(XV.x, W0.x, a0.x); a0.y = fmaf(XV.y, W0.x, a0.y);     \
    a0.z = fmaf(XV.z, W0.x, a0.z); a0.w = fmaf(XV.w, W0.x, a0.w);     \
    a1.x = fmaf(XV.x, W0.y, a1.x); a1.y = fmaf(XV.y, W0.y, a1.y);     \
    a1.z = fmaf(XV.z, W0.y, a1.z); a1.w = fmaf(XV.w, W0.y, a1.w);     \
    a2.x = fmaf(XV.x, W0.z, a2.x); a2.y = fmaf(XV.y, W0.z, a2.y);     \
    a2.z = fmaf(XV.z, W0.z, a2.z); a2.w = fmaf(XV.w, W0.z, a2.w);     \
    a3.x = fmaf(XV.x, W0.w, a3.x); a3.y = fmaf(XV.y, W0.w, a3.y);     \
    a3.z = fmaf(XV.z, W0.w, a3.z); a3.w = fmaf(XV.w, W0.w, a3.w);     \
    a4.x = fmaf(XV.x, W1.x, a4.x); a4.y = fmaf(XV.y, W1.x, a4.y);     \
    a4.z = fmaf(XV.z, W1.x, a4.z); a4.w = fmaf(XV.w, W1.x, a4.w);     \
    a5.x = fmaf(XV.x, W1.y, a5.x); a5.y = fmaf(XV.y, W1.y, a5.y);     \
    a5.z = fmaf(XV.z, W1.y, a5.z); a5.w = fmaf(XV.w, W1.y, a5.w);     \
    a6.x = fmaf(XV.x, W1.z, a6.x); a6.y = fmaf(XV.y, W1.z, a6.y);     \
    a6.z = fmaf(XV.z, W1.z, a6.z); a6.w = fmaf(XV.w, W1.z, a6.w);     \
    a7.x = fmaf(XV.x, W1.w, a7.x); a7.y = fmaf(XV.y, W1.w, a7.y);     \
    a7.z = fmaf(XV.z, W1.w, a7.z); a7.w = fmaf(XV.w, W1.w, a7.w);

#define WLOAD8(MM, W0, W1)                                            \
    { const float* ar = att + (MM);                                   \
      W0.x = __expf(ar[0]);            W0.y = __expf(ar[M]);          \
      W0.z = __expf(ar[2 * M]);        W0.w = __expf(ar[3 * M]);      \
      W1.x = __expf(ar[4 * M]);        W1.y = __expf(ar[5 * M]);      \
      W1.z = __expf(ar[6 * M]);        W1.w = __expf(ar[7 * M]); }

// Kernel 1 (no predecessors):
//   blocks [0, B*KSL): pooling. Block = (graph g, slice k); segment bounds by
//     binary search in sorted batch; weights exp(att[h][m]) computed on the
//     fly (unnormalized; 1/sum folded into reduceB). 4 waves split the slice;
//     wave lanes = (node 0..7) x (chan-group 0..7); 8 head float4 acc/lane;
//     LDS cross-wave reduce -> psum[block][256]. No atomics, no fences.
//   blocks [B*KSL, +H*PB): partial expsums of att rows -> partials[].
__global__ __launch_bounds__(256, 5) void poolA_kernel(
        const float* __restrict__ x, const int* __restrict__ batch,
        const float* __restrict__ att, float* __restrict__ psum,
        float* __restrict__ partials, int M, int Ntot, int B) {
    const int bid = blockIdx.x;
    const int npool = B * KSL;

    if (bid >= npool) {                       // ---- partial expsum blocks ----
        const int pbid = bid - npool;         // 0 .. H*PB-1
        const int h = pbid / PB;
        const int p = pbid % PB;
        const int s0 = (int)(((long)M * p) / PB);
        const int s1 = (int)(((long)M * (p + 1)) / PB);
        const float* __restrict__ row = att + (size_t)h * M;
        __shared__ float red[4];
        float s = 0.f;
        for (int i = s0 + threadIdx.x; i < s1; i += 256) s += __expf(row[i]);
        s = wred_sum(s);
        if ((threadIdx.x & 63) == 0) red[threadIdx.x >> 6] = s;
        __syncthreads();
        if (threadIdx.x == 0)
            partials[h * PB + p] = red[0] + red[1] + red[2] + red[3];
        return;
    }

    // ---- pooling blocks ----
    const int g  = bid >> 5;
    const int k  = bid & (KSL - 1);
    const int wv = threadIdx.x >> 6;
    const int lane = threadIdx.x & 63;
    const int cg = lane & 7;
    const int no = lane >> 3;
    const int c  = cg << 2;

    const int s0 = lower_bound(batch, Ntot, g);
    const int s1 = lower_bound(batch, Ntot, g + 1);
    const int L  = s1 - s0;
    const int sb = s0 + (int)(((long)L * k) >> 5);
    const int sl = (s0 + (int)(((long)L * (k + 1)) >> 5)) - sb;
    int       n    = sb + (sl * wv) / 4;
    const int nEnd = sb + (sl * (wv + 1)) / 4;

    float4 a0 = {0,0,0,0}, a1 = {0,0,0,0}, a2 = {0,0,0,0}, a3 = {0,0,0,0};
    float4 a4 = {0,0,0,0}, a5 = {0,0,0,0}, a6 = {0,0,0,0}, a7 = {0,0,0,0};

    int m = n % M;
    while (n < nEnd) {
        const int run = min(nEnd - n, M - m);   // weight slot = global n % M
        const float* xb = x + (size_t)(n + no) * C + c;
        const int full = run & ~7;
        int i = 0;
#pragma unroll 2
        for (; i < full; i += 8) {
            const float4 xv = *(const float4*)(xb + (size_t)i * C);
            float4 wv0, wv1;
            WLOAD8(m + i + no, wv0, wv1)
            FMA8(xv, wv0, wv1)
        }
        const int rem = run - full;
        if (rem) {
            const int off = (no < rem) ? no : 0;   // clamp to valid node
            const float4 xv = *(const float4*)(x + (size_t)(n + i + off) * C + c);
            float4 wv0 = {0,0,0,0}, wv1 = {0,0,0,0};
            if (no < rem) { WLOAD8(m + i + no, wv0, wv1) }
            FMA8(xv, wv0, wv1)
        }
        n += run;
        m += run;
        if (m >= M) m = 0;
    }

    // reduce over node-offset axis within wave
    a0 = red4_no(a0); a1 = red4_no(a1); a2 = red4_no(a2); a3 = red4_no(a3);
    a4 = red4_no(a4); a5 = red4_no(a5); a6 = red4_no(a6); a7 = red4_no(a7);

    // cross-wave reduce via LDS, then wave 0 writes the block's psum slot
    __shared__ float4 sacc[4][H][8];
    if (no == 0) {
        sacc[wv][0][cg] = a0; sacc[wv][1][cg] = a1;
        sacc[wv][2][cg] = a2; sacc[wv][3][cg] = a3;
        sacc[wv][4][cg] = a4; sacc[wv][5][cg] = a5;
        sacc[wv][6][cg] = a6; sacc[wv][7][cg] = a7;
    }
    __syncthreads();
    if (wv == 0) {
        const int hh = lane >> 3;
        const int cc = lane & 7;
        float4 s  = sacc[0][hh][cc];
        float4 t1 = sacc[1][hh][cc];
        float4 t2 = sacc[2][hh][cc];
        float4 t3 = sacc[3][hh][cc];
        s.x += t1.x + t2.x + t3.x;
        s.y += t1.y + t2.y + t3.y;
        s.z += t1.z + t2.z + t3.z;
        s.w += t1.w + t2.w + t3.w;
        float* o = psum + ((size_t)bid << 8) + (hh << 5) + (cc << 2);
        *(float4*)o = s;
    }
}

// Kernel 2: out[g][h*32+c] = inv[h] * sum_k psum[g*KSL+k][h*32+c];
// inv[h] = 1/sum(partials[h*PB..]) -- softmax normalization folded here.
__global__ __launch_bounds__(256) void reduceB_kernel(
        const float* __restrict__ psum, const float* __restrict__ partials,
        float* __restrict__ out) {
    __shared__ float sinv[H];
    if (threadIdx.x < H) {
        float s = 0.f;
#pragma unroll
        for (int k = 0; k < PB; ++k) s += partials[threadIdx.x * PB + k];
        sinv[threadIdx.x] = 1.0f / s;
    }
    __syncthreads();
    const int g = blockIdx.x;
    const int i = threadIdx.x;
    const float* p = psum + ((size_t)g << 13) + i;   // g*KSL*256
    float s = 0.f;
#pragma unroll
    for (int k = 0; k < KSL; ++k) s += p[(size_t)k << 8];
    out[(g << 8) + i] = s * sinv[i >> 5];
}

extern "C" void kernel_launch(void* const* d_in, const int* in_sizes, int n_in,
                              void* d_out, int out_size, void* d_ws, size_t ws_size,
                              hipStream_t stream) {
    const float* x     = (const float*)d_in[0];
    const int*   batch = (const int*)d_in[1];
    const float* att   = (const float*)d_in[2];
    float*       out   = (float*)d_out;

    const int Ntot = in_sizes[0] / C;   // total nodes
    const int M    = in_sizes[2] / H;   // nodes per graph slot axis
    const int B    = out_size / HC;     // graphs

    // ws layout: [partials H*PB f @0][psum B*KSL*256 f @4096]
    float* partials = (float*)d_ws;
    float* psum     = (float*)((char*)d_ws + 4096);

    // k1: pooling (binary-search bounds, on-the-fly exp) + partial expsums
    poolA_kernel<<<B * KSL + H * PB, 256, 0, stream>>>(
        x, batch, att, psum, partials, M, Ntot, B);

    // k2: reduction + softmax normalization (fully overwrites out)
    reduceB_kernel<<<B, 256, 0, stream>>>(psum, partials, out);
}

// Round 15
// 40.088 us; speedup vs baseline: 1.1048x; 1.1048x over previous
//
#include <hip/hip_runtime.h>
#include <math.h>

#define H 8
#define C 32
#define HC 256
#define KSL 32    // slices per graph
#define PB 16     // partial expsum blocks per head

__device__ __forceinline__ float wred_sum(float v) {
#pragma unroll
    for (int o = 32; o; o >>= 1) v += __shfl_xor(v, o, 64);
    return v;
}
__device__ __forceinline__ float4 red4_no(float4 v) {
#pragma unroll
    for (int o = 8; o < 64; o <<= 1) {
        v.x += __shfl_xor(v.x, o, 64);
        v.y += __shfl_xor(v.y, o, 64);
        v.z += __shfl_xor(v.z, o, 64);
        v.w += __shfl_xor(v.w, o, 64);
    }
    return v;
}
__device__ __forceinline__ int lower_bound(const int* __restrict__ a, int n, int key) {
    int lo = 0, hi = n;
    while (lo < hi) {                 // wave-uniform: all lanes same path
        const int mid = (lo + hi) >> 1;
        if (a[mid] < key) lo = mid + 1; else hi = mid;
    }
    return lo;
}

// k1 small prep (no batch scan -- segment bounds are found by binary search
// inside poolA, proven in R14):
//   blocks [0, tb)      : wtabT[m*8+h] = exp(att[h][m])  (UNNORMALIZED;
//                         1/sum folded into reduceB)
//   blocks [tb, tb+H*PB): partial expsums
__global__ __launch_bounds__(256) void prep_kernel(
        const float* __restrict__ att, float* __restrict__ wtabT,
        float* __restrict__ partials, int M, int tb) {
    const int bid = blockIdx.x;
    if (bid < tb) {
        const int idx = bid * 256 + threadIdx.x;
        if (idx < H * M) {
            const int hh = idx & (H - 1);
            const int mm = idx >> 3;
            wtabT[idx] = __expf(att[(size_t)hh * M + mm]);
        }
    } else {
        const int pbid = bid - tb;               // 0 .. H*PB-1
        const int h = pbid / PB;
        const int p = pbid % PB;
        const int s0 = (int)(((long)M * p) / PB);
        const int s1 = (int)(((long)M * (p + 1)) / PB);
        const float* __restrict__ row = att + (size_t)h * M;
        __shared__ float red[4];
        float s = 0.f;
        for (int i = s0 + threadIdx.x; i < s1; i += 256) s += __expf(row[i]);
        s = wred_sum(s);
        if ((threadIdx.x & 63) == 0) red[threadIdx.x >> 6] = s;
        __syncthreads();
        if (threadIdx.x == 0)
            partials[h * PB + p] = red[0] + red[1] + red[2] + red[3];
    }
}

#define FMA8(XV, W0, W1)                                              \
    a0.x = fmaf(XV.x, W0.x, a0.x); a0.y = fmaf(XV.y, W0.x, a0.y);     \
    a0.z = fmaf(XV.z, W0.x, a0.z); a0.w = fmaf(XV.w, W0.x, a0.w);     \
    a1.x = fmaf(XV.x, W0.y, a1.x); a1.y = fmaf(XV.y, W0.y, a1.y);     \
    a1.z = fmaf(XV.z, W0.y, a1.z); a1.w = fmaf(XV.w, W0.y, a1.w);     \
    a2.x = fmaf(XV.x, W0.z, a2.x); a2.y = fmaf(XV.y, W0.z, a2.y);     \
    a2.z = fmaf(XV.z, W0.z, a2.z); a2.w = fmaf(XV.w, W0.z, a2.w);     \
    a3.x = fmaf(XV.x, W0.w, a3.x); a3.y = fmaf(XV.y, W0.w, a3.y);     \
    a3.z = fmaf(XV.z, W0.w, a3.z); a3.w = fmaf(XV.w, W0.w, a3.w);     \
    a4.x = fmaf(XV.x, W1.x, a4.x); a4.y = fmaf(XV.y, W1.x, a4.y);     \
    a4.z = fmaf(XV.z, W1.x, a4.z); a4.w = fmaf(XV.w, W1.x, a4.w);     \
    a5.x = fmaf(XV.x, W1.y, a5.x); a5.y = fmaf(XV.y, W1.y, a5.y);     \
    a5.z = fmaf(XV.z, W1.y, a5.z); a5.w = fmaf(XV.w, W1.y, a5.w);     \
    a6.x = fmaf(XV.x, W1.z, a6.x); a6.y = fmaf(XV.y, W1.z, a6.y);     \
    a6.z = fmaf(XV.z, W1.z, a6.z); a6.w = fmaf(XV.w, W1.z, a6.w);     \
    a7.x = fmaf(XV.x, W1.w, a7.x); a7.y = fmaf(XV.y, W1.w, a7.y);     \
    a7.z = fmaf(XV.z, W1.w, a7.z); a7.w = fmaf(XV.w, W1.w, a7.w);

// Phase A: block = (graph g, slice k). Segment bounds via binary search in
// sorted batch (R14-proven). 4 waves split the slice; wave lanes =
// (node 0..7) x (chan-group 0..7); 8 head float4 accumulators/lane; weights
// from contiguous wtabT (R11-proven). LDS cross-wave reduce -> psum[block].
// No atomics, no device-scope fences (R9/R10 lesson).
__global__ __launch_bounds__(256, 5) void poolA_kernel(
        const float* __restrict__ x, const int* __restrict__ batch,
        const float* __restrict__ wtabT, float* __restrict__ psum,
        int M, int Ntot) {
    const int g  = blockIdx.x >> 5;
    const int k  = blockIdx.x & (KSL - 1);
    const int wv = threadIdx.x >> 6;
    const int lane = threadIdx.x & 63;
    const int cg = lane & 7;
    const int no = lane >> 3;
    const int c  = cg << 2;

    const int s0 = lower_bound(batch, Ntot, g);
    const int s1 = lower_bound(batch, Ntot, g + 1);
    const int L  = s1 - s0;
    const int sb = s0 + (int)(((long)L * k) >> 5);
    const int sl = (s0 + (int)(((long)L * (k + 1)) >> 5)) - sb;
    int       n    = sb + (sl * wv) / 4;
    const int nEnd = sb + (sl * (wv + 1)) / 4;

    float4 a0 = {0,0,0,0}, a1 = {0,0,0,0}, a2 = {0,0,0,0}, a3 = {0,0,0,0};
    float4 a4 = {0,0,0,0}, a5 = {0,0,0,0}, a6 = {0,0,0,0}, a7 = {0,0,0,0};

    int m = n % M;
    while (n < nEnd) {
        const int run = min(nEnd - n, M - m);   // weight slot = global n % M
        const float* xb = x + (size_t)(n + no) * C + c;
        const float* wb = wtabT + ((size_t)(m + no) << 3);
        const int full = run & ~7;
        int i = 0;
#pragma unroll 4
        for (; i < full; i += 8) {
            const float4 xv  = *(const float4*)(xb + (size_t)i * C);
            const float4 wv0 = *(const float4*)(wb + (size_t)i * 8);
            const float4 wv1 = *(const float4*)(wb + (size_t)i * 8 + 4);
            FMA8(xv, wv0, wv1)
        }
        const int rem = run - full;
        if (rem) {
            const int off = (no < rem) ? no : 0;   // clamp to valid node
            const float4 xv = *(const float4*)(x + (size_t)(n + i + off) * C + c);
            float4 wv0 = {0,0,0,0}, wv1 = {0,0,0,0};
            if (no < rem) {
                const float* wb2 = wtabT + ((size_t)(m + i + no) << 3);
                wv0 = *(const float4*)(wb2);
                wv1 = *(const float4*)(wb2 + 4);
            }
            FMA8(xv, wv0, wv1)
        }
        n += run;
        m += run;
        if (m >= M) m = 0;
    }

    // reduce over node-offset axis within wave
    a0 = red4_no(a0); a1 = red4_no(a1); a2 = red4_no(a2); a3 = red4_no(a3);
    a4 = red4_no(a4); a5 = red4_no(a5); a6 = red4_no(a6); a7 = red4_no(a7);

    // cross-wave reduce via LDS, then wave 0 writes the block's psum slot
    __shared__ float4 sacc[4][H][8];
    if (no == 0) {
        sacc[wv][0][cg] = a0; sacc[wv][1][cg] = a1;
        sacc[wv][2][cg] = a2; sacc[wv][3][cg] = a3;
        sacc[wv][4][cg] = a4; sacc[wv][5][cg] = a5;
        sacc[wv][6][cg] = a6; sacc[wv][7][cg] = a7;
    }
    __syncthreads();
    if (wv == 0) {
        const int hh = lane >> 3;
        const int cc = lane & 7;
        float4 s  = sacc[0][hh][cc];
        float4 t1 = sacc[1][hh][cc];
        float4 t2 = sacc[2][hh][cc];
        float4 t3 = sacc[3][hh][cc];
        s.x += t1.x + t2.x + t3.x;
        s.y += t1.y + t2.y + t3.y;
        s.z += t1.z + t2.z + t3.z;
        s.w += t1.w + t2.w + t3.w;
        float* o = psum + ((size_t)blockIdx.x << 8) + (hh << 5) + (cc << 2);
        *(float4*)o = s;
    }
}

// Kernel 3: out[g][h*32+c] = inv[h] * sum_k psum[g*KSL+k][h*32+c];
// inv[h] = 1/sum(partials[h*PB..]) -- softmax normalization folded here.
__global__ __launch_bounds__(256) void reduceB_kernel(
        const float* __restrict__ psum, const float* __restrict__ partials,
        float* __restrict__ out) {
    __shared__ float sinv[H];
    if (threadIdx.x < H) {
        float s = 0.f;
#pragma unroll
        for (int k = 0; k < PB; ++k) s += partials[threadIdx.x * PB + k];
        sinv[threadIdx.x] = 1.0f / s;
    }
    __syncthreads();
    const int g = blockIdx.x;
    const int i = threadIdx.x;
    const float* p = psum + ((size_t)g << 13) + i;   // g*KSL*256
    float s = 0.f;
#pragma unroll
    for (int k = 0; k < KSL; ++k) s += p[(size_t)k << 8];
    out[(g << 8) + i] = s * sinv[i >> 5];
}

extern "C" void kernel_launch(void* const* d_in, const int* in_sizes, int n_in,
                              void* d_out, int out_size, void* d_ws, size_t ws_size,
                              hipStream_t stream) {
    const float* x     = (const float*)d_in[0];
    const int*   batch = (const int*)d_in[1];
    const float* att   = (const float*)d_in[2];
    float*       out   = (float*)d_out;

    const int Ntot = in_sizes[0] / C;   // total nodes
    const int M    = in_sizes[2] / H;   // nodes per graph slot axis
    const int B    = out_size / HC;     // graphs

    // ws layout: [partials H*PB f @0][wtabT H*M f @4096][psum after, aligned]
    float* partials = (float*)d_ws;
    float* wtabT    = (float*)((char*)d_ws + 4096);
    const size_t ps_off = (4096 + (size_t)H * M * sizeof(float) + 255) & ~(size_t)255;
    float* psum     = (float*)((char*)d_ws + ps_off);

    // k1: small prep (weight table + partial expsums; NO batch scan)
    const int tb = (H * M + 255) / 256;
    prep_kernel<<<tb + H * PB, 256, 0, stream>>>(att, wtabT, partials, M, tb);

    // k2: pooling (binary-search bounds, contiguous weight table)
    poolA_kernel<<<B * KSL, 256, 0, stream>>>(x, batch, wtabT, psum, M, Ntot);

    // k3: reduction + softmax normalization (fully overwrites out)
    reduceB_kernel<<<B, 256, 0, stream>>>(psum, partials, out);
}